// Round 12
// baseline (42.926 us; speedup 1.0000x reference)
//
#include <hip/hip_runtime.h>
#include <math.h>
#include <climits>

#define BLOCK 512
#define NW (BLOCK / 64)                 // 8 waves -> max 4 blocks/CU -> grid
                                        // 2048 = TWO generations (overlap)
#define NCHUNK 3
#define REGCAP (NCHUNK * BLOCK * 4)     // 6144 aligned elements per block
#define LARGE_NEG (-1.0e9f)
#define SCORE_EPS 1e-6f
#define RANDP 0.1f
#define PROB_EPS 1e-12f
#define F32EPS 1.1920928955078125e-7f   // torch.finfo(float32).eps

// scalar windowed lower_bound: first idx with batch[idx] >= target.
// Window ghat +/- 16384 (>11 sigma for multinomial edge counts), verified,
// full-range fallback so correctness never depends on the distribution.
__device__ __forceinline__ int scalar_lb(const int* __restrict__ batch,
                                         int E, int G, int target) {
  const long long ghat =
      (long long)target * (long long)E / (long long)(G > 0 ? G : 1);
  long long wlo = ghat - 16384, whi = ghat + 16384;
  int lo = wlo > 0 ? (int)wlo : 0;
  int hi = whi < (long long)E ? (int)whi : E;
  while (lo < hi) {
    const int mid = (lo + hi) >> 1;
    if (batch[mid] < target) lo = mid + 1; else hi = mid;
  }
  bool ok = (lo == 0 || batch[lo - 1] < target) &&
            (lo == E || batch[lo] >= target);
  if (!ok) {                            // window missed: full-range redo
    lo = 0; hi = E;
    while (lo < hi) {
      const int mid = (lo + hi) >> 1;
      if (batch[mid] < target) lo = mid + 1; else hi = mid;
    }
  }
  return lo;
}

// ---------- single kernel: one 512-thread workgroup per graph --------------
// Prologue (concurrent, one barrier): thread 0 -> start = lb(g); thread 64 ->
//   end = lb(g+1); wave 2 -> valid_edges format detect on shared 1KB sample.
// Body (r10 logic): predicated float4 loads; t = log(w)+r with branchless
//   online softmax (om, os); smax/ssum/vcnt/argmax inline; ONE fused 8-wave
//   reduce; scalar plumbing; store pass from registers.
__global__ __launch_bounds__(BLOCK) void
gfn_main(const float* __restrict__ scores,
         const float* __restrict__ resid,
         const float* __restrict__ stop_resid,
         const void* __restrict__ validp,
         const int* __restrict__ batch,
         float* __restrict__ out, int E, int G) {
  __shared__ float redf[6 * NW];        // smax|ssum|vcnt|om|os|bv  x NW waves
  __shared__ int redi[NW];
  __shared__ int sb[2];
  __shared__ int sflag;

  const int g = blockIdx.x;
  const unsigned char* vb = (const unsigned char*)validp;
  const int* vi = (const int*)validp;
  const int wid = (int)(threadIdx.x >> 6);
  const int lane = (int)(threadIdx.x & 63);

  // ---- fused prologue ----
  if (threadIdx.x == 0) {
    sb[0] = scalar_lb(batch, E, G, g);
  } else if (threadIdx.x == 64) {
    sb[1] = scalar_lb(batch, E, G, g + 1);
  } else if (wid == 2) {
    const unsigned int* vwords = (const unsigned int*)validp;
    const int sampleBytes = (E < 1024) ? (E & ~3) : 1024;
    const int nwords = sampleBytes >> 2;
    int cnt = 0;
    for (int w = lane; w < nwords; w += 64) {
      const unsigned int x = vwords[w];
      cnt += ((x & 0x000000FFu) != 0) + ((x & 0x0000FF00u) != 0) +
             ((x & 0x00FF0000u) != 0) + ((x & 0xFF000000u) != 0);
    }
#pragma unroll
    for (int o = 32; o >= 1; o >>= 1) cnt += __shfl_xor(cnt, o);
    if (lane == 0) sflag = (2 * cnt > sampleBytes) ? 1 : 0;
  }
  __syncthreads();
  const int start = sb[0];
  const int end = sb[1];
  const bool byteFmt = (sflag != 0);
  const int abase = start & ~3;          // 16B-aligned segment base

  if ((E & 3) == 0 && (end - abase) <= REGCAP) {
    // =================== fast path: t in registers, online reduce ==========
    const int t4 = (int)threadIdx.x * 4;
    float c[NCHUNK][4];                  // t (or LARGE_NEG), static indexing
    float smax = 0.f, ssum = 0.f;
    int vcnt = 0;
    float om = LARGE_NEG, os = 0.f;      // online (max, expsum) over t
    float bv = -INFINITY;                // argmax over t (monotone equiv to
    int bi = INT_MAX;                    //   reference log_sample argmax)

#pragma unroll
    for (int j = 0; j < NCHUNK; ++j) {
      const int e0 = abase + j * (BLOCK * 4) + t4;
      if (e0 < end) {   // e0%4==0 & E%4==0 -> e0+3 <= E-1 (safe f4 load)
        const float4 s4 = *(const float4*)(scores + e0);
        const float4 r4 = *(const float4*)(resid + e0);
        unsigned int m;
        if (byteFmt) {
          const unsigned int u = *(const unsigned int*)(vb + e0);
          m = ((u & 0x000000FFu) ? 1u : 0u) | ((u & 0x0000FF00u) ? 2u : 0u) |
              ((u & 0x00FF0000u) ? 4u : 0u) | ((u & 0xFF000000u) ? 8u : 0u);
        } else {
          const int4 u = *(const int4*)(vi + e0);
          m = (u.x ? 1u : 0u) | (u.y ? 2u : 0u) | (u.z ? 4u : 0u) | (u.w ? 8u : 0u);
        }
        const float ss[4] = {s4.x, s4.y, s4.z, s4.w};
        const float rr[4] = {r4.x, r4.y, r4.z, r4.w};
#pragma unroll
        for (int k = 0; k < 4; ++k) {
          const int e = e0 + k;
          const bool ok = ((m >> k) & 1u) && (e >= start) && (e < end);
          float t = LARGE_NEG;
          if (ok) {
            const float w = fmaxf(ss[k], SCORE_EPS);
            smax = fmaxf(smax, w);
            ssum += w;
            ++vcnt;
            t = __logf(w) + rr[k];
            // branchless online update (no divergent dual-exp paths)
            const float nm = fmaxf(om, t);
            os = os * __expf(om - nm) + __expf(t - nm);  // first iter: 0*0+1
            om = nm;
            if (t > bv || (t == bv && e < bi)) { bv = t; bi = e; }
          }
          c[j][k] = t;
        }
      } else {
#pragma unroll
        for (int k = 0; k < 4; ++k) c[j][k] = LARGE_NEG;
      }
    }

    // ---- single fused reduce: wave shuffle cascade over everything --------
#pragma unroll
    for (int o = 32; o >= 1; o >>= 1) {
      smax = fmaxf(smax, __shfl_xor(smax, o));
      ssum += __shfl_xor(ssum, o);
      vcnt += __shfl_xor(vcnt, o);
      const float m2v = __shfl_xor(om, o);
      const float s2v = __shfl_xor(os, o);
      const float nm = fmaxf(om, m2v);
      os = os * __expf(om - nm) + s2v * __expf(m2v - nm);
      om = nm;
      const float v2 = __shfl_xor(bv, o);
      const int i2 = __shfl_xor(bi, o);
      if (v2 > bv || (v2 == bv && i2 < bi)) { bv = v2; bi = i2; }
    }
    if (lane == 0) {
      redf[wid] = smax; redf[NW + wid] = ssum; redf[2 * NW + wid] = (float)vcnt;
      redf[3 * NW + wid] = om; redf[4 * NW + wid] = os; redf[5 * NW + wid] = bv;
      redi[wid] = bi;
    }
    __syncthreads();
    smax = redf[0]; ssum = redf[NW]; float vc = redf[2 * NW];
    om = redf[3 * NW]; os = redf[4 * NW];
    bv = redf[5 * NW]; bi = redi[0];
#pragma unroll
    for (int w = 1; w < NW; ++w) {
      smax = fmaxf(smax, redf[w]);
      ssum += redf[NW + w];
      vc += redf[2 * NW + w];
      const float mb = redf[3 * NW + w], sb2 = redf[4 * NW + w];
      const float nm = fmaxf(om, mb);            // online-merge wave pairs
      os = os * __expf(om - nm) + sb2 * __expf(mb - nm);
      om = nm;
      const float v2 = redf[5 * NW + w]; const int i2 = redi[w];
      if (v2 > bv || (v2 == bv && i2 < bi)) { bv = v2; bi = i2; }
    }

    // ---- per-graph scalars (computed by every thread; all scalar math) ----
    // exp(log w - mj1) == w/M with M = max(smax,1) = exp(mj1);
    // max((log w - ld1) + r) == tmax - ld1;  Sum exp(c-mj2) == os*exp(m2-mj2).
    const float M = fmaxf(smax, 1.f);
    const float invM = 1.f / M;
    const float ld1 = __logf(M) + __logf(ssum * invM + invM + F32EPS);
    const float m2 = om - ld1;               // max combined edge logit
    const float ss2 = stop_resid[g] - ld1;   // combined stop logit
    const float mj2 = fmaxf(m2, ss2);
    const float s2 = os * __expf(m2 - mj2);  // edge exp-sum at mj2 scale
    const float ld2 = mj2 + __logf(s2 + __expf(ss2 - mj2) + F32EPS);
    const float clean_stop = ss2 - ld2;
    const float invt = 1.f / fmaxf(vc + 1.f, 1.f);
    const float off3 = ld1 + ld2;            // clean = t - off3

    // ---- store pass: clean_log_edge from registers ------------------------
#pragma unroll
    for (int j = 0; j < NCHUNK; ++j) {
      const int e0 = abase + j * (BLOCK * 4) + t4;
      if (e0 < end) {
        float ov[4];
#pragma unroll
        for (int k = 0; k < 4; ++k) {
          const float t = c[j][k];
          ov[k] = (t != LARGE_NEG) ? (t - off3) : LARGE_NEG;
        }
        if (e0 >= start && e0 + 4 <= end) {
          *(float4*)(out + e0) = make_float4(ov[0], ov[1], ov[2], ov[3]);
        } else {
#pragma unroll
          for (int k = 0; k < 4; ++k) {
            const int e = e0 + k;
            if (e >= start && e < end) out[e] = ov[k];
          }
        }
      }
    }
    if (threadIdx.x == 0) {
      const bool anyvalid = (bi != INT_MAX);
      const float wclean = bv - off3;      // winner's clean_log_edge
      float bvls = LARGE_NEG;              // best log_sample_edge (ref formula)
      if (anyvalid) {
        const float p = (1.f - RANDP) * __expf(wclean) + RANDP * invt;
        bvls = __logf(fmaxf(p, PROB_EPS));
      }
      const float ssp = (1.f - RANDP) * __expf(clean_stop) + RANDP * invt;
      const float lss = __logf(fmaxf(ssp, PROB_EPS));
      const bool take_stop = (lss >= bvls);
      out[E + g]         = clean_stop;                         // output 1
      out[E + G + g]     = take_stop ? (float)end : (float)bi; // output 2
      out[E + 2 * G + g] = take_stop ? clean_stop : wclean;    // output 3
    }
    return;
  }

  // =================== fallback: 5-pass global reread (n > REGCAP) =========
  const int n = end - start;
  auto load_l = [&](int e) -> float {
    float s = scores[e];
    int v = byteFmt ? (int)vb[e] : vi[e];
    return v ? __logf(fmaxf(s, SCORE_EPS)) : LARGE_NEG;
  };

  float m1 = LARGE_NEG, vc = 0.f;
  for (int i = threadIdx.x; i < n; i += BLOCK) {
    float l = load_l(start + i);
    m1 = fmaxf(m1, l);
    if (l != LARGE_NEG) vc += 1.f;
  }
#pragma unroll
  for (int o = 32; o >= 1; o >>= 1) {
    m1 = fmaxf(m1, __shfl_xor(m1, o));
    vc += __shfl_xor(vc, o);
  }
  if (lane == 0) { redf[wid] = m1; redf[NW + wid] = vc; }
  __syncthreads();
  m1 = redf[0]; vc = redf[NW];
#pragma unroll
  for (int w = 1; w < NW; ++w) { m1 = fmaxf(m1, redf[w]); vc += redf[NW + w]; }
  __syncthreads();

  const float mj1 = fmaxf(m1, 0.f);
  float s1 = 0.f;
  for (int i = threadIdx.x; i < n; i += BLOCK)
    s1 += __expf(load_l(start + i) - mj1);
#pragma unroll
  for (int o = 32; o >= 1; o >>= 1) s1 += __shfl_xor(s1, o);
  if (lane == 0) redf[wid] = s1;
  __syncthreads();
  s1 = redf[0];
#pragma unroll
  for (int w = 1; w < NW; ++w) s1 += redf[w];
  __syncthreads();
  const float ld1 = mj1 + __logf(s1 + __expf(-mj1) + F32EPS);

  float m2 = LARGE_NEG;
  for (int i = threadIdx.x; i < n; i += BLOCK) {
    float l = load_l(start + i);
    float cc = (l != LARGE_NEG) ? (l - ld1 + resid[start + i]) : LARGE_NEG;
    m2 = fmaxf(m2, cc);
  }
#pragma unroll
  for (int o = 32; o >= 1; o >>= 1) m2 = fmaxf(m2, __shfl_xor(m2, o));
  if (lane == 0) redf[wid] = m2;
  __syncthreads();
  m2 = redf[0];
#pragma unroll
  for (int w = 1; w < NW; ++w) m2 = fmaxf(m2, redf[w]);
  __syncthreads();

  const float ss2 = stop_resid[g] - ld1;
  const float mj2 = fmaxf(m2, ss2);
  float s2 = 0.f;
  for (int i = threadIdx.x; i < n; i += BLOCK) {
    float l = load_l(start + i);
    float cc = (l != LARGE_NEG) ? (l - ld1 + resid[start + i]) : LARGE_NEG;
    s2 += __expf(cc - mj2);
  }
#pragma unroll
  for (int o = 32; o >= 1; o >>= 1) s2 += __shfl_xor(s2, o);
  if (lane == 0) redf[wid] = s2;
  __syncthreads();
  s2 = redf[0];
#pragma unroll
  for (int w = 1; w < NW; ++w) s2 += redf[w];
  __syncthreads();
  const float ld2 = mj2 + __logf(s2 + __expf(ss2 - mj2) + F32EPS);
  const float clean_stop = ss2 - ld2;
  const float invt = 1.f / fmaxf(vc + 1.f, 1.f);

  float bv = -INFINITY; int bi = INT_MAX; float bc = 0.f;
  for (int i = threadIdx.x; i < n; i += BLOCK) {
    const int e = start + i;
    float l = load_l(e);
    float cc = (l != LARGE_NEG) ? (l - ld1 + resid[e]) : LARGE_NEG;
    const bool v = (cc != LARGE_NEG);
    const float clean = cc - ld2;
    out[e] = v ? clean : LARGE_NEG;
    float ls;
    if (v) {
      const float p = (1.f - RANDP) * __expf(clean) + RANDP * invt;
      ls = __logf(fmaxf(p, PROB_EPS));
    } else ls = LARGE_NEG;
    if (ls > bv || (ls == bv && e < bi)) { bv = ls; bi = e; bc = clean; }
  }
#pragma unroll
  for (int o = 32; o >= 1; o >>= 1) {
    const float v2 = __shfl_xor(bv, o);
    const int i2 = __shfl_xor(bi, o);
    const float c2 = __shfl_xor(bc, o);
    if (v2 > bv || (v2 == bv && i2 < bi)) { bv = v2; bi = i2; bc = c2; }
  }
  if (lane == 0) { redf[wid] = bv; redf[NW + wid] = bc; redi[wid] = bi; }
  __syncthreads();
  if (threadIdx.x == 0) {
    bv = redf[0]; bi = redi[0]; bc = redf[NW];
    for (int w = 1; w < NW; ++w) {
      if (redf[w] > bv || (redf[w] == bv && redi[w] < bi)) {
        bv = redf[w]; bi = redi[w]; bc = redf[NW + w];
      }
    }
    const float ssp = (1.f - RANDP) * __expf(clean_stop) + RANDP * invt;
    const float lss = __logf(fmaxf(ssp, PROB_EPS));
    const bool take_stop = (lss >= bv);
    out[E + g]         = clean_stop;
    out[E + G + g]     = take_stop ? (float)end : (float)bi;
    out[E + 2 * G + g] = take_stop ? clean_stop : bc;
  }
}

extern "C" void kernel_launch(void* const* d_in, const int* in_sizes, int n_in,
                              void* d_out, int out_size, void* d_ws, size_t ws_size,
                              hipStream_t stream) {
  const float* scores     = (const float*)d_in[0];
  const float* resid      = (const float*)d_in[1];
  const float* stop_resid = (const float*)d_in[2];
  const void*  validp     = d_in[3];
  const int*   batch      = (const int*)d_in[4];
  const int E = in_sizes[0];
  const int G = in_sizes[2];

  gfn_main<<<G, BLOCK, 0, stream>>>(scores, resid, stop_resid, validp, batch,
                                    (float*)d_out, E, G);
}

// Round 13
// 33.892 us; speedup vs baseline: 1.2665x; 1.2665x over previous
//
#include <hip/hip_runtime.h>
#include <math.h>
#include <climits>

#define BLOCK 256
#define NCHUNK 5
#define REGCAP (NCHUNK * 1024)          // 5120 aligned elements per block
#define LARGE_NEG (-1.0e9f)
#define SCORE_EPS 1e-6f
#define RANDP 0.1f
#define PROB_EPS 1e-12f
#define F32EPS 1.1920928955078125e-7f   // torch.finfo(float32).eps

// ---------- single kernel: one workgroup per graph -------------------------
// Prologue (concurrent, one barrier):
//   wave 0: BOTH segment bounds via 64-lane lockstep fan-out lower_bound —
//     lanes 0-31 target g, lanes 32-63 target g+1. Window ghat +/- 16384
//     (>11 sigma for multinomial edge counts). Each round: 32 probes/target
//     (one vector load), ballot+popcount, window /32. 3 rounds + verify
//     (vs 15 dependent scalar probes). Full-range scalar fallback keeps
//     correctness distribution-independent.
//   wave 1: valid_edges format detect on shared 1KB sample (byte-bool ~90%
//     nonzero bytes | int32 ~22.5% | f32 ~45%; threshold 50%).
// Body (r10, verified 33.2us): predicated float4 loads; t = log(w)+r with
//   branchless online softmax (om, os); smax/ssum/vcnt/argmax inline; ONE
//   fused reduce; scalar plumbing (r11-validated one-log ld1); store pass
//   from registers.
__global__ __launch_bounds__(BLOCK) void
gfn_main(const float* __restrict__ scores,
         const float* __restrict__ resid,
         const float* __restrict__ stop_resid,
         const void* __restrict__ validp,
         const int* __restrict__ batch,
         float* __restrict__ out, int E, int G) {
  __shared__ float redf[24];
  __shared__ int redi[4];
  __shared__ int sb[2];
  __shared__ int sflag;

  const int g = blockIdx.x;
  const unsigned char* vb = (const unsigned char*)validp;
  const int* vi = (const int*)validp;
  const int wid = (int)(threadIdx.x >> 6);
  const int lane = (int)(threadIdx.x & 63);

  // ---- fused prologue ----
  if (wid == 0) {
    // -- dual fan-out lower_bound: first idx with batch[idx] >= tgt --
    const int half = lane >> 5;          // 0 -> target g, 1 -> target g+1
    const int sub = lane & 31;
    const int tgt = g + half;
    const long long ghat =
        (long long)tgt * (long long)E / (long long)(G > 0 ? G : 1);
    long long wlo = ghat - 16384; if (wlo < 0) wlo = 0;
    long long whi = ghat + 16384; if (whi > (long long)E) whi = E;
    int lo = (int)wlo, hi = (int)whi;    // invariant (if window ok): ptr in [lo,hi]
#pragma unroll
    for (int r = 0; r < 3; ++r) {
      const int width = hi - lo;
      const int stride = (width + 31) >> 5;        // ceil(width/32)
      bool pred = false;
      if (stride > 0) {
        const long long pos = (long long)lo + (long long)sub * (long long)stride;
        if (pos < (long long)hi) pred = batch[(int)pos] < tgt;  // pos in [lo,hi) subset [0,E)
      }
      const unsigned long long m = __ballot(pred);
      const int c = (int)__popcll(half ? (m >> 32) : (m & 0xffffffffull));
      if (stride > 0) {
        // pred monotone-decreasing in sub: probes [0,c) true, [c,32) false
        const int nlo = (c > 0) ? (lo + (c - 1) * stride + 1) : lo;
        const long long pc = (long long)lo + (long long)c * (long long)stride;
        const int nhi = (c < 32 && pc < (long long)hi) ? (int)pc : hi;
        lo = nlo; hi = nhi;              // new width <= stride-1 -> 3 rounds => width 0
      }
    }
    if (sub == 0) {                      // lanes 0 and 32: verify + publish
      int r0 = lo;
      const bool ok = (r0 == 0 || batch[r0 - 1] < tgt) &&
                      (r0 == E || batch[r0] >= tgt);
      if (!ok) {                         // window missed: full-range redo
        int flo = 0, fhi = E;
        while (flo < fhi) {
          const int mid = (flo + fhi) >> 1;
          if (batch[mid] < tgt) flo = mid + 1; else fhi = mid;
        }
        r0 = flo;
      }
      sb[half] = r0;
    }
  } else if (wid == 1) {
    const unsigned int* vwords = (const unsigned int*)validp;
    const int sampleBytes = (E < 1024) ? (E & ~3) : 1024;
    const int nwords = sampleBytes >> 2;
    int cnt = 0;
    for (int w = lane; w < nwords; w += 64) {
      const unsigned int x = vwords[w];
      cnt += ((x & 0x000000FFu) != 0) + ((x & 0x0000FF00u) != 0) +
             ((x & 0x00FF0000u) != 0) + ((x & 0xFF000000u) != 0);
    }
#pragma unroll
    for (int o = 32; o >= 1; o >>= 1) cnt += __shfl_xor(cnt, o);
    if (lane == 0) sflag = (2 * cnt > sampleBytes) ? 1 : 0;
  }
  __syncthreads();
  const int start = sb[0];
  const int end = sb[1];
  const bool byteFmt = (sflag != 0);
  const int abase = start & ~3;          // 16B-aligned segment base

  if ((E & 3) == 0 && (end - abase) <= REGCAP) {
    // =================== fast path: t in registers, online reduce ==========
    const int t4 = (int)threadIdx.x * 4;
    float c[NCHUNK][4];                  // t (or LARGE_NEG), static indexing
    float smax = 0.f, ssum = 0.f;
    int vcnt = 0;
    float om = LARGE_NEG, os = 0.f;      // online (max, expsum) over t
    float bv = -INFINITY;                // argmax over t (monotone equiv to
    int bi = INT_MAX;                    //   reference log_sample argmax)

#pragma unroll
    for (int j = 0; j < NCHUNK; ++j) {
      const int e0 = abase + j * 1024 + t4;
      if (e0 < end) {   // e0%4==0 & E%4==0 -> e0+3 <= E-1 (safe f4 load)
        const float4 s4 = *(const float4*)(scores + e0);
        const float4 r4 = *(const float4*)(resid + e0);
        unsigned int m;
        if (byteFmt) {
          const unsigned int u = *(const unsigned int*)(vb + e0);
          m = ((u & 0x000000FFu) ? 1u : 0u) | ((u & 0x0000FF00u) ? 2u : 0u) |
              ((u & 0x00FF0000u) ? 4u : 0u) | ((u & 0xFF000000u) ? 8u : 0u);
        } else {
          const int4 u = *(const int4*)(vi + e0);
          m = (u.x ? 1u : 0u) | (u.y ? 2u : 0u) | (u.z ? 4u : 0u) | (u.w ? 8u : 0u);
        }
        const float ss[4] = {s4.x, s4.y, s4.z, s4.w};
        const float rr[4] = {r4.x, r4.y, r4.z, r4.w};
#pragma unroll
        for (int k = 0; k < 4; ++k) {
          const int e = e0 + k;
          const bool ok = ((m >> k) & 1u) && (e >= start) && (e < end);
          float t = LARGE_NEG;
          if (ok) {
            const float w = fmaxf(ss[k], SCORE_EPS);
            smax = fmaxf(smax, w);
            ssum += w;
            ++vcnt;
            t = __logf(w) + rr[k];
            // branchless online update (no divergent dual-exp paths)
            const float nm = fmaxf(om, t);
            os = os * __expf(om - nm) + __expf(t - nm);  // first iter: 0*0+1
            om = nm;
            if (t > bv || (t == bv && e < bi)) { bv = t; bi = e; }
          }
          c[j][k] = t;
        }
      } else {
#pragma unroll
        for (int k = 0; k < 4; ++k) c[j][k] = LARGE_NEG;
      }
    }

    // ---- single fused reduce: wave shuffle cascade over everything --------
#pragma unroll
    for (int o = 32; o >= 1; o >>= 1) {
      smax = fmaxf(smax, __shfl_xor(smax, o));
      ssum += __shfl_xor(ssum, o);
      vcnt += __shfl_xor(vcnt, o);
      const float m2v = __shfl_xor(om, o);
      const float s2v = __shfl_xor(os, o);
      const float nm = fmaxf(om, m2v);
      os = os * __expf(om - nm) + s2v * __expf(m2v - nm);
      om = nm;
      const float v2 = __shfl_xor(bv, o);
      const int i2 = __shfl_xor(bi, o);
      if (v2 > bv || (v2 == bv && i2 < bi)) { bv = v2; bi = i2; }
    }
    if (lane == 0) {
      redf[wid] = smax; redf[4 + wid] = ssum; redf[8 + wid] = (float)vcnt;
      redf[12 + wid] = om; redf[16 + wid] = os; redf[20 + wid] = bv;
      redi[wid] = bi;
    }
    __syncthreads();
    smax = fmaxf(fmaxf(redf[0], redf[1]), fmaxf(redf[2], redf[3]));
    ssum = (redf[4] + redf[5]) + (redf[6] + redf[7]);
    const float vc = (redf[8] + redf[9]) + (redf[10] + redf[11]);
    om = redf[12]; os = redf[16];
#pragma unroll
    for (int w = 1; w < 4; ++w) {        // online-merge 4 wave pairs
      const float mb = redf[12 + w], sb2 = redf[16 + w];
      const float nm = fmaxf(om, mb);
      os = os * __expf(om - nm) + sb2 * __expf(mb - nm);
      om = nm;
    }
    bv = redf[20]; bi = redi[0];
#pragma unroll
    for (int w = 1; w < 4; ++w) {
      const float v2 = redf[20 + w]; const int i2 = redi[w];
      if (v2 > bv || (v2 == bv && i2 < bi)) { bv = v2; bi = i2; }
    }

    // ---- per-graph scalars (computed by every thread; all scalar math) ----
    // ld1 = log M + log(ssum/M + 1/M + EPS) == log(ssum + 1 + M*EPS)  [r11]
    // max((log w - ld1) + r) == tmax - ld1; Sum exp(c-mj2) == os*exp(m2-mj2).
    const float M = fmaxf(smax, 1.f);
    const float ld1 = __logf(ssum + 1.f + M * F32EPS);
    const float m2 = om - ld1;               // max combined edge logit
    const float ss2 = stop_resid[g] - ld1;   // combined stop logit
    const float mj2 = fmaxf(m2, ss2);
    const float s2 = os * __expf(m2 - mj2);  // edge exp-sum at mj2 scale
    const float ld2 = mj2 + __logf(s2 + __expf(ss2 - mj2) + F32EPS);
    const float clean_stop = ss2 - ld2;
    const float invt = 1.f / fmaxf(vc + 1.f, 1.f);
    const float off3 = ld1 + ld2;            // clean = t - off3

    // ---- store pass: clean_log_edge from registers ------------------------
#pragma unroll
    for (int j = 0; j < NCHUNK; ++j) {
      const int e0 = abase + j * 1024 + t4;
      if (e0 < end) {
        float ov[4];
#pragma unroll
        for (int k = 0; k < 4; ++k) {
          const float t = c[j][k];
          ov[k] = (t != LARGE_NEG) ? (t - off3) : LARGE_NEG;
        }
        if (e0 >= start && e0 + 4 <= end) {
          *(float4*)(out + e0) = make_float4(ov[0], ov[1], ov[2], ov[3]);
        } else {
#pragma unroll
          for (int k = 0; k < 4; ++k) {
            const int e = e0 + k;
            if (e >= start && e < end) out[e] = ov[k];
          }
        }
      }
    }
    if (threadIdx.x == 0) {
      const bool anyvalid = (bi != INT_MAX);
      const float wclean = bv - off3;      // winner's clean_log_edge
      float bvls = LARGE_NEG;              // best log_sample_edge (ref formula)
      if (anyvalid) {
        const float p = (1.f - RANDP) * __expf(wclean) + RANDP * invt;
        bvls = __logf(fmaxf(p, PROB_EPS));
      }
      const float ssp = (1.f - RANDP) * __expf(clean_stop) + RANDP * invt;
      const float lss = __logf(fmaxf(ssp, PROB_EPS));
      const bool take_stop = (lss >= bvls);
      out[E + g]         = clean_stop;                         // output 1
      out[E + G + g]     = take_stop ? (float)end : (float)bi; // output 2
      out[E + 2 * G + g] = take_stop ? clean_stop : wclean;    // output 3
    }
    return;
  }

  // =================== fallback: 5-pass global reread (n > REGCAP) =========
  const int n = end - start;
  auto load_l = [&](int e) -> float {
    float s = scores[e];
    int v = byteFmt ? (int)vb[e] : vi[e];
    return v ? __logf(fmaxf(s, SCORE_EPS)) : LARGE_NEG;
  };

  float m1 = LARGE_NEG, vc = 0.f;
  for (int i = threadIdx.x; i < n; i += BLOCK) {
    float l = load_l(start + i);
    m1 = fmaxf(m1, l);
    if (l != LARGE_NEG) vc += 1.f;
  }
#pragma unroll
  for (int o = 32; o >= 1; o >>= 1) {
    m1 = fmaxf(m1, __shfl_xor(m1, o));
    vc += __shfl_xor(vc, o);
  }
  if (lane == 0) { redf[wid] = m1; redf[4 + wid] = vc; }
  __syncthreads();
  m1 = fmaxf(fmaxf(redf[0], redf[1]), fmaxf(redf[2], redf[3]));
  vc = (redf[4] + redf[5]) + (redf[6] + redf[7]);
  __syncthreads();

  const float mj1 = fmaxf(m1, 0.f);
  float s1 = 0.f;
  for (int i = threadIdx.x; i < n; i += BLOCK)
    s1 += __expf(load_l(start + i) - mj1);
#pragma unroll
  for (int o = 32; o >= 1; o >>= 1) s1 += __shfl_xor(s1, o);
  if (lane == 0) redf[wid] = s1;
  __syncthreads();
  s1 = (redf[0] + redf[1]) + (redf[2] + redf[3]);
  __syncthreads();
  const float ld1 = mj1 + __logf(s1 + __expf(-mj1) + F32EPS);

  float m2 = LARGE_NEG;
  for (int i = threadIdx.x; i < n; i += BLOCK) {
    float l = load_l(start + i);
    float cc = (l != LARGE_NEG) ? (l - ld1 + resid[start + i]) : LARGE_NEG;
    m2 = fmaxf(m2, cc);
  }
#pragma unroll
  for (int o = 32; o >= 1; o >>= 1) m2 = fmaxf(m2, __shfl_xor(m2, o));
  if (lane == 0) redf[wid] = m2;
  __syncthreads();
  m2 = fmaxf(fmaxf(redf[0], redf[1]), fmaxf(redf[2], redf[3]));
  __syncthreads();

  const float ss2 = stop_resid[g] - ld1;
  const float mj2 = fmaxf(m2, ss2);
  float s2 = 0.f;
  for (int i = threadIdx.x; i < n; i += BLOCK) {
    float l = load_l(start + i);
    float cc = (l != LARGE_NEG) ? (l - ld1 + resid[start + i]) : LARGE_NEG;
    s2 += __expf(cc - mj2);
  }
#pragma unroll
  for (int o = 32; o >= 1; o >>= 1) s2 += __shfl_xor(s2, o);
  if (lane == 0) redf[wid] = s2;
  __syncthreads();
  s2 = (redf[0] + redf[1]) + (redf[2] + redf[3]);
  __syncthreads();
  const float ld2 = mj2 + __logf(s2 + __expf(ss2 - mj2) + F32EPS);
  const float clean_stop = ss2 - ld2;
  const float invt = 1.f / fmaxf(vc + 1.f, 1.f);

  float bv = -INFINITY; int bi = INT_MAX; float bc = 0.f;
  for (int i = threadIdx.x; i < n; i += BLOCK) {
    const int e = start + i;
    float l = load_l(e);
    float cc = (l != LARGE_NEG) ? (l - ld1 + resid[e]) : LARGE_NEG;
    const bool v = (cc != LARGE_NEG);
    const float clean = cc - ld2;
    out[e] = v ? clean : LARGE_NEG;
    float ls;
    if (v) {
      const float p = (1.f - RANDP) * __expf(clean) + RANDP * invt;
      ls = __logf(fmaxf(p, PROB_EPS));
    } else ls = LARGE_NEG;
    if (ls > bv || (ls == bv && e < bi)) { bv = ls; bi = e; bc = clean; }
  }
#pragma unroll
  for (int o = 32; o >= 1; o >>= 1) {
    const float v2 = __shfl_xor(bv, o);
    const int i2 = __shfl_xor(bi, o);
    const float c2 = __shfl_xor(bc, o);
    if (v2 > bv || (v2 == bv && i2 < bi)) { bv = v2; bi = i2; bc = c2; }
  }
  if (lane == 0) { redf[wid] = bv; redf[4 + wid] = bc; redi[wid] = bi; }
  __syncthreads();
  if (threadIdx.x == 0) {
    bv = redf[0]; bi = redi[0]; bc = redf[4];
    for (int w = 1; w < 4; ++w) {
      if (redf[w] > bv || (redf[w] == bv && redi[w] < bi)) {
        bv = redf[w]; bi = redi[w]; bc = redf[4 + w];
      }
    }
    const float ssp = (1.f - RANDP) * __expf(clean_stop) + RANDP * invt;
    const float lss = __logf(fmaxf(ssp, PROB_EPS));
    const bool take_stop = (lss >= bv);
    out[E + g]         = clean_stop;
    out[E + G + g]     = take_stop ? (float)end : (float)bi;
    out[E + 2 * G + g] = take_stop ? clean_stop : bc;
  }
}

extern "C" void kernel_launch(void* const* d_in, const int* in_sizes, int n_in,
                              void* d_out, int out_size, void* d_ws, size_t ws_size,
                              hipStream_t stream) {
  const float* scores     = (const float*)d_in[0];
  const float* resid      = (const float*)d_in[1];
  const float* stop_resid = (const float*)d_in[2];
  const void*  validp     = d_in[3];
  const int*   batch      = (const int*)d_in[4];
  const int E = in_sizes[0];
  const int G = in_sizes[2];

  gfn_main<<<G, BLOCK, 0, stream>>>(scores, resid, stop_resid, validp, batch,
                                    (float*)d_out, E, G);
}

// Round 14
// 33.116 us; speedup vs baseline: 1.2962x; 1.0234x over previous
//
#include <hip/hip_runtime.h>
#include <math.h>
#include <climits>

#define BLOCK 256
#define NCHUNK 5
#define REGCAP (NCHUNK * 1024)          // 5120 aligned elements per block
#define LARGE_NEG (-1.0e9f)
#define SCORE_EPS 1e-6f
#define RANDP 0.1f
#define PROB_EPS 1e-12f
#define F32EPS 1.1920928955078125e-7f   // torch.finfo(float32).eps

// scalar windowed lower_bound: first idx with batch[idx] >= target.
// Window ghat +/- 8192 (>5.6 sigma for multinomial cumulative counts),
// verified, full-range fallback: correctness never depends on distribution.
__device__ __forceinline__ int scalar_lb(const int* __restrict__ batch,
                                         int E, int G, int target) {
  const long long ghat =
      (long long)target * (long long)E / (long long)(G > 0 ? G : 1);
  long long wlo = ghat - 8192, whi = ghat + 8192;
  int lo = wlo > 0 ? (int)wlo : 0;
  int hi = whi < (long long)E ? (int)whi : E;
  while (lo < hi) {
    const int mid = (lo + hi) >> 1;
    if (batch[mid] < target) lo = mid + 1; else hi = mid;
  }
  bool ok = (lo == 0 || batch[lo - 1] < target) &&
            (lo == E || batch[lo] >= target);
  if (!ok) {                            // window missed: full-range redo
    lo = 0; hi = E;
    while (lo < hi) {
      const int mid = (lo + hi) >> 1;
      if (batch[mid] < target) lo = mid + 1; else hi = mid;
    }
  }
  return lo;
}

// ---------- single kernel: one workgroup per graph (r10 + reg-pin) ---------
// Prologue (concurrent, one barrier): thread 0 -> start = lb(g); thread 64 ->
//   end = lb(g+1); wave 2 -> valid_edges format detect on shared 1KB sample.
// Body: predicated float4 loads; t = log(w)+r with branchless online softmax
//   (om, os); smax/ssum/vcnt/argmax inline; ONE fused reduce; scalar plumbing;
//   store pass from registers.
// KEY (r14): c[] values are made OPAQUE via asm after the load loop, so the
//   compiler cannot rematerialize them in the store pass by re-loading
//   scores/resid and recomputing log (VGPR 32 across r3-r13 proved it did).
__global__ __launch_bounds__(BLOCK) void
gfn_main(const float* __restrict__ scores,
         const float* __restrict__ resid,
         const float* __restrict__ stop_resid,
         const void* __restrict__ validp,
         const int* __restrict__ batch,
         float* __restrict__ out, int E, int G) {
  __shared__ float redf[24];
  __shared__ int redi[4];
  __shared__ int sb[2];
  __shared__ int sflag;

  const int g = blockIdx.x;
  const unsigned char* vb = (const unsigned char*)validp;
  const int* vi = (const int*)validp;
  const int wid = (int)(threadIdx.x >> 6);
  const int lane = (int)(threadIdx.x & 63);

  // ---- fused prologue ----
  if (threadIdx.x == 0) {
    sb[0] = scalar_lb(batch, E, G, g);
  } else if (threadIdx.x == 64) {
    sb[1] = scalar_lb(batch, E, G, g + 1);
  } else if (wid == 2) {
    const unsigned int* vwords = (const unsigned int*)validp;
    const int sampleBytes = (E < 1024) ? (E & ~3) : 1024;
    const int nwords = sampleBytes >> 2;
    int cnt = 0;
    for (int w = lane; w < nwords; w += 64) {
      const unsigned int x = vwords[w];
      cnt += ((x & 0x000000FFu) != 0) + ((x & 0x0000FF00u) != 0) +
             ((x & 0x00FF0000u) != 0) + ((x & 0xFF000000u) != 0);
    }
#pragma unroll
    for (int o = 32; o >= 1; o >>= 1) cnt += __shfl_xor(cnt, o);
    if (lane == 0) sflag = (2 * cnt > sampleBytes) ? 1 : 0;
  }
  __syncthreads();
  const int start = sb[0];
  const int end = sb[1];
  const bool byteFmt = (sflag != 0);
  const int abase = start & ~3;          // 16B-aligned segment base

  if ((E & 3) == 0 && (end - abase) <= REGCAP) {
    // =================== fast path: t in registers, online reduce ==========
    const int t4 = (int)threadIdx.x * 4;
    float c[NCHUNK][4];                  // t (or LARGE_NEG), static indexing
    float smax = 0.f, ssum = 0.f;
    int vcnt = 0;
    float om = LARGE_NEG, os = 0.f;      // online (max, expsum) over t
    float bv = -INFINITY;                // argmax over t (monotone equiv to
    int bi = INT_MAX;                    //   reference log_sample argmax)

#pragma unroll
    for (int j = 0; j < NCHUNK; ++j) {
      const int e0 = abase + j * 1024 + t4;
      if (e0 < end) {   // e0%4==0 & E%4==0 -> e0+3 <= E-1 (safe f4 load)
        const float4 s4 = *(const float4*)(scores + e0);
        const float4 r4 = *(const float4*)(resid + e0);
        unsigned int m;
        if (byteFmt) {
          const unsigned int u = *(const unsigned int*)(vb + e0);
          m = ((u & 0x000000FFu) ? 1u : 0u) | ((u & 0x0000FF00u) ? 2u : 0u) |
              ((u & 0x00FF0000u) ? 4u : 0u) | ((u & 0xFF000000u) ? 8u : 0u);
        } else {
          const int4 u = *(const int4*)(vi + e0);
          m = (u.x ? 1u : 0u) | (u.y ? 2u : 0u) | (u.z ? 4u : 0u) | (u.w ? 8u : 0u);
        }
        const float ss[4] = {s4.x, s4.y, s4.z, s4.w};
        const float rr[4] = {r4.x, r4.y, r4.z, r4.w};
#pragma unroll
        for (int k = 0; k < 4; ++k) {
          const int e = e0 + k;
          const bool ok = ((m >> k) & 1u) && (e >= start) && (e < end);
          float t = LARGE_NEG;
          if (ok) {
            const float w = fmaxf(ss[k], SCORE_EPS);
            smax = fmaxf(smax, w);
            ssum += w;
            ++vcnt;
            t = __logf(w) + rr[k];
            // branchless online update (no divergent dual-exp paths)
            const float nm = fmaxf(om, t);
            os = os * __expf(om - nm) + __expf(t - nm);  // first iter: 0*0+1
            om = nm;
            if (t > bv || (t == bv && e < bi)) { bv = t; bi = e; }
          }
          c[j][k] = t;
        }
      } else {
#pragma unroll
        for (int k = 0; k < 4; ++k) c[j][k] = LARGE_NEG;
      }
    }

    // ---- PIN c[] in VGPRs: opaque to the optimizer -> no rematerialization
    //      (without this, VGPR=32 proves the store pass re-loads + re-logs)
#pragma unroll
    for (int j = 0; j < NCHUNK; ++j)
#pragma unroll
      for (int k = 0; k < 4; ++k)
        asm volatile("" : "+v"(c[j][k]));

    // ---- single fused reduce: wave shuffle cascade over everything --------
#pragma unroll
    for (int o = 32; o >= 1; o >>= 1) {
      smax = fmaxf(smax, __shfl_xor(smax, o));
      ssum += __shfl_xor(ssum, o);
      vcnt += __shfl_xor(vcnt, o);
      const float m2v = __shfl_xor(om, o);
      const float s2v = __shfl_xor(os, o);
      const float nm = fmaxf(om, m2v);
      os = os * __expf(om - nm) + s2v * __expf(m2v - nm);
      om = nm;
      const float v2 = __shfl_xor(bv, o);
      const int i2 = __shfl_xor(bi, o);
      if (v2 > bv || (v2 == bv && i2 < bi)) { bv = v2; bi = i2; }
    }
    if (lane == 0) {
      redf[wid] = smax; redf[4 + wid] = ssum; redf[8 + wid] = (float)vcnt;
      redf[12 + wid] = om; redf[16 + wid] = os; redf[20 + wid] = bv;
      redi[wid] = bi;
    }
    __syncthreads();
    smax = fmaxf(fmaxf(redf[0], redf[1]), fmaxf(redf[2], redf[3]));
    ssum = (redf[4] + redf[5]) + (redf[6] + redf[7]);
    const float vc = (redf[8] + redf[9]) + (redf[10] + redf[11]);
    om = redf[12]; os = redf[16];
#pragma unroll
    for (int w = 1; w < 4; ++w) {        // online-merge 4 wave pairs
      const float mb = redf[12 + w], sb2 = redf[16 + w];
      const float nm = fmaxf(om, mb);
      os = os * __expf(om - nm) + sb2 * __expf(mb - nm);
      om = nm;
    }
    bv = redf[20]; bi = redi[0];
#pragma unroll
    for (int w = 1; w < 4; ++w) {
      const float v2 = redf[20 + w]; const int i2 = redi[w];
      if (v2 > bv || (v2 == bv && i2 < bi)) { bv = v2; bi = i2; }
    }

    // ---- per-graph scalars (computed by every thread; all scalar math) ----
    // ld1 = log M + log(ssum/M + 1/M + EPS) == log(ssum + 1 + M*EPS)  [r11]
    // max((log w - ld1) + r) == tmax - ld1; Sum exp(c-mj2) == os*exp(m2-mj2).
    const float M = fmaxf(smax, 1.f);
    const float ld1 = __logf(ssum + 1.f + M * F32EPS);
    const float m2 = om - ld1;               // max combined edge logit
    const float ss2 = stop_resid[g] - ld1;   // combined stop logit
    const float mj2 = fmaxf(m2, ss2);
    const float s2 = os * __expf(m2 - mj2);  // edge exp-sum at mj2 scale
    const float ld2 = mj2 + __logf(s2 + __expf(ss2 - mj2) + F32EPS);
    const float clean_stop = ss2 - ld2;
    const float invt = 1.f / fmaxf(vc + 1.f, 1.f);
    const float off3 = ld1 + ld2;            // clean = t - off3

    // ---- store pass: clean_log_edge from (pinned) registers ---------------
#pragma unroll
    for (int j = 0; j < NCHUNK; ++j) {
      const int e0 = abase + j * 1024 + t4;
      if (e0 < end) {
        float ov[4];
#pragma unroll
        for (int k = 0; k < 4; ++k) {
          const float t = c[j][k];
          ov[k] = (t != LARGE_NEG) ? (t - off3) : LARGE_NEG;
        }
        if (e0 >= start && e0 + 4 <= end) {
          *(float4*)(out + e0) = make_float4(ov[0], ov[1], ov[2], ov[3]);
        } else {
#pragma unroll
          for (int k = 0; k < 4; ++k) {
            const int e = e0 + k;
            if (e >= start && e < end) out[e] = ov[k];
          }
        }
      }
    }
    if (threadIdx.x == 0) {
      const bool anyvalid = (bi != INT_MAX);
      const float wclean = bv - off3;      // winner's clean_log_edge
      float bvls = LARGE_NEG;              // best log_sample_edge (ref formula)
      if (anyvalid) {
        const float p = (1.f - RANDP) * __expf(wclean) + RANDP * invt;
        bvls = __logf(fmaxf(p, PROB_EPS));
      }
      const float ssp = (1.f - RANDP) * __expf(clean_stop) + RANDP * invt;
      const float lss = __logf(fmaxf(ssp, PROB_EPS));
      const bool take_stop = (lss >= bvls);
      out[E + g]         = clean_stop;                         // output 1
      out[E + G + g]     = take_stop ? (float)end : (float)bi; // output 2
      out[E + 2 * G + g] = take_stop ? clean_stop : wclean;    // output 3
    }
    return;
  }

  // =================== fallback: 5-pass global reread (n > REGCAP) =========
  const int n = end - start;
  auto load_l = [&](int e) -> float {
    float s = scores[e];
    int v = byteFmt ? (int)vb[e] : vi[e];
    return v ? __logf(fmaxf(s, SCORE_EPS)) : LARGE_NEG;
  };

  float m1 = LARGE_NEG, vc = 0.f;
  for (int i = threadIdx.x; i < n; i += BLOCK) {
    float l = load_l(start + i);
    m1 = fmaxf(m1, l);
    if (l != LARGE_NEG) vc += 1.f;
  }
#pragma unroll
  for (int o = 32; o >= 1; o >>= 1) {
    m1 = fmaxf(m1, __shfl_xor(m1, o));
    vc += __shfl_xor(vc, o);
  }
  if (lane == 0) { redf[wid] = m1; redf[4 + wid] = vc; }
  __syncthreads();
  m1 = fmaxf(fmaxf(redf[0], redf[1]), fmaxf(redf[2], redf[3]));
  vc = (redf[4] + redf[5]) + (redf[6] + redf[7]);
  __syncthreads();

  const float mj1 = fmaxf(m1, 0.f);
  float s1 = 0.f;
  for (int i = threadIdx.x; i < n; i += BLOCK)
    s1 += __expf(load_l(start + i) - mj1);
#pragma unroll
  for (int o = 32; o >= 1; o >>= 1) s1 += __shfl_xor(s1, o);
  if (lane == 0) redf[wid] = s1;
  __syncthreads();
  s1 = (redf[0] + redf[1]) + (redf[2] + redf[3]);
  __syncthreads();
  const float ld1 = mj1 + __logf(s1 + __expf(-mj1) + F32EPS);

  float m2 = LARGE_NEG;
  for (int i = threadIdx.x; i < n; i += BLOCK) {
    float l = load_l(start + i);
    float cc = (l != LARGE_NEG) ? (l - ld1 + resid[start + i]) : LARGE_NEG;
    m2 = fmaxf(m2, cc);
  }
#pragma unroll
  for (int o = 32; o >= 1; o >>= 1) m2 = fmaxf(m2, __shfl_xor(m2, o));
  if (lane == 0) redf[wid] = m2;
  __syncthreads();
  m2 = fmaxf(fmaxf(redf[0], redf[1]), fmaxf(redf[2], redf[3]));
  __syncthreads();

  const float ss2 = stop_resid[g] - ld1;
  const float mj2 = fmaxf(m2, ss2);
  float s2 = 0.f;
  for (int i = threadIdx.x; i < n; i += BLOCK) {
    float l = load_l(start + i);
    float cc = (l != LARGE_NEG) ? (l - ld1 + resid[start + i]) : LARGE_NEG;
    s2 += __expf(cc - mj2);
  }
#pragma unroll
  for (int o = 32; o >= 1; o >>= 1) s2 += __shfl_xor(s2, o);
  if (lane == 0) redf[wid] = s2;
  __syncthreads();
  s2 = (redf[0] + redf[1]) + (redf[2] + redf[3]);
  __syncthreads();
  const float ld2 = mj2 + __logf(s2 + __expf(ss2 - mj2) + F32EPS);
  const float clean_stop = ss2 - ld2;
  const float invt = 1.f / fmaxf(vc + 1.f, 1.f);

  float bv = -INFINITY; int bi = INT_MAX; float bc = 0.f;
  for (int i = threadIdx.x; i < n; i += BLOCK) {
    const int e = start + i;
    float l = load_l(e);
    float cc = (l != LARGE_NEG) ? (l - ld1 + resid[e]) : LARGE_NEG;
    const bool v = (cc != LARGE_NEG);
    const float clean = cc - ld2;
    out[e] = v ? clean : LARGE_NEG;
    float ls;
    if (v) {
      const float p = (1.f - RANDP) * __expf(clean) + RANDP * invt;
      ls = __logf(fmaxf(p, PROB_EPS));
    } else ls = LARGE_NEG;
    if (ls > bv || (ls == bv && e < bi)) { bv = ls; bi = e; bc = clean; }
  }
#pragma unroll
  for (int o = 32; o >= 1; o >>= 1) {
    const float v2 = __shfl_xor(bv, o);
    const int i2 = __shfl_xor(bi, o);
    const float c2 = __shfl_xor(bc, o);
    if (v2 > bv || (v2 == bv && i2 < bi)) { bv = v2; bi = i2; bc = c2; }
  }
  if (lane == 0) { redf[wid] = bv; redf[4 + wid] = bc; redi[wid] = bi; }
  __syncthreads();
  if (threadIdx.x == 0) {
    bv = redf[0]; bi = redi[0]; bc = redf[4];
    for (int w = 1; w < 4; ++w) {
      if (redf[w] > bv || (redf[w] == bv && redi[w] < bi)) {
        bv = redf[w]; bi = redi[w]; bc = redf[4 + w];
      }
    }
    const float ssp = (1.f - RANDP) * __expf(clean_stop) + RANDP * invt;
    const float lss = __logf(fmaxf(ssp, PROB_EPS));
    const bool take_stop = (lss >= bv);
    out[E + g]         = clean_stop;
    out[E + G + g]     = take_stop ? (float)end : (float)bi;
    out[E + 2 * G + g] = take_stop ? clean_stop : bc;
  }
}

extern "C" void kernel_launch(void* const* d_in, const int* in_sizes, int n_in,
                              void* d_out, int out_size, void* d_ws, size_t ws_size,
                              hipStream_t stream) {
  const float* scores     = (const float*)d_in[0];
  const float* resid      = (const float*)d_in[1];
  const float* stop_resid = (const float*)d_in[2];
  const void*  validp     = d_in[3];
  const int*   batch      = (const int*)d_in[4];
  const int E = in_sizes[0];
  const int G = in_sizes[2];

  gfn_main<<<G, BLOCK, 0, stream>>>(scores, resid, stop_resid, validp, batch,
                                    (float*)d_out, E, G);
}

// Round 15
// 32.813 us; speedup vs baseline: 1.3082x; 1.0092x over previous
//
#include <hip/hip_runtime.h>
#include <math.h>
#include <climits>

#define BLOCK 256
#define NCHUNK 5
#define REGCAP (NCHUNK * 1024)          // 5120 aligned elements per block
#define LARGE_NEG (-1.0e9f)
#define SCORE_EPS 1e-6f
#define RANDP 0.1f
#define PROB_EPS 1e-12f
#define F32EPS 1.1920928955078125e-7f   // torch.finfo(float32).eps

// scalar windowed lower_bound: first idx with batch[idx] >= target.
// Window ghat +/- 8192 (>5.6 sigma for multinomial cumulative counts),
// verified, full-range fallback: correctness never depends on distribution.
__device__ __forceinline__ int scalar_lb(const int* __restrict__ batch,
                                         int E, int G, int target) {
  const long long ghat =
      (long long)target * (long long)E / (long long)(G > 0 ? G : 1);
  long long wlo = ghat - 8192, whi = ghat + 8192;
  int lo = wlo > 0 ? (int)wlo : 0;
  int hi = whi < (long long)E ? (int)whi : E;
  while (lo < hi) {
    const int mid = (lo + hi) >> 1;
    if (batch[mid] < target) lo = mid + 1; else hi = mid;
  }
  bool ok = (lo == 0 || batch[lo - 1] < target) &&
            (lo == E || batch[lo] >= target);
  if (!ok) {                            // window missed: full-range redo
    lo = 0; hi = E;
    while (lo < hi) {
      const int mid = (lo + hi) >> 1;
      if (batch[mid] < target) lo = mid + 1; else hi = mid;
    }
  }
  return lo;
}

// ---------- single kernel: one workgroup per graph (r10 body + T1 swizzle) -
// T1: chunked bijective XCD swizzle. Default dispatch round-robins
//   consecutive blocks across 8 XCD L2s, so the batch probe lines shared by
//   neighboring graphs (block g's lb(g+1) == block g+1's lb(g+1)) are
//   fetched into different L2s at L3/HBM latency. Swizzle gives each XCD a
//   contiguous G/8-graph range: shared search levels become L2 hits and
//   each XCD streams a contiguous input slice. Perf heuristic only.
// Prologue (concurrent, one barrier): thread 0 -> start = lb(g); thread 64
//   -> end = lb(g+1); wave 2 -> valid format detect on shared 1KB sample.
// Body (r10, verified): predicated float4 loads; t = log(w)+r with
//   branchless online softmax (om, os); smax/ssum/vcnt/argmax inline; ONE
//   fused reduce; scalar plumbing (r11 one-log ld1); store from registers.
__global__ __launch_bounds__(BLOCK) void
gfn_main(const float* __restrict__ scores,
         const float* __restrict__ resid,
         const float* __restrict__ stop_resid,
         const void* __restrict__ validp,
         const int* __restrict__ batch,
         float* __restrict__ out, int E, int G) {
  __shared__ float redf[24];
  __shared__ int redi[4];
  __shared__ int sb[2];
  __shared__ int sflag;

  // ---- T1: XCD-chunked bijective block->graph swizzle (G%8==0 path) ----
  const int bid = (int)blockIdx.x;
  const int g = ((G & 7) == 0) ? ((bid & 7) * (G >> 3) + (bid >> 3)) : bid;

  const unsigned char* vb = (const unsigned char*)validp;
  const int* vi = (const int*)validp;
  const int wid = (int)(threadIdx.x >> 6);
  const int lane = (int)(threadIdx.x & 63);

  // ---- fused prologue ----
  if (threadIdx.x == 0) {
    sb[0] = scalar_lb(batch, E, G, g);
  } else if (threadIdx.x == 64) {
    sb[1] = scalar_lb(batch, E, G, g + 1);
  } else if (wid == 2) {
    const unsigned int* vwords = (const unsigned int*)validp;
    const int sampleBytes = (E < 1024) ? (E & ~3) : 1024;
    const int nwords = sampleBytes >> 2;
    int cnt = 0;
    for (int w = lane; w < nwords; w += 64) {
      const unsigned int x = vwords[w];
      cnt += ((x & 0x000000FFu) != 0) + ((x & 0x0000FF00u) != 0) +
             ((x & 0x00FF0000u) != 0) + ((x & 0xFF000000u) != 0);
    }
#pragma unroll
    for (int o = 32; o >= 1; o >>= 1) cnt += __shfl_xor(cnt, o);
    if (lane == 0) sflag = (2 * cnt > sampleBytes) ? 1 : 0;
  }
  __syncthreads();
  const int start = sb[0];
  const int end = sb[1];
  const bool byteFmt = (sflag != 0);
  const int abase = start & ~3;          // 16B-aligned segment base

  if ((E & 3) == 0 && (end - abase) <= REGCAP) {
    // =================== fast path: t in registers, online reduce ==========
    const int t4 = (int)threadIdx.x * 4;
    float c[NCHUNK][4];                  // t (or LARGE_NEG), static indexing
    float smax = 0.f, ssum = 0.f;
    int vcnt = 0;
    float om = LARGE_NEG, os = 0.f;      // online (max, expsum) over t
    float bv = -INFINITY;                // argmax over t (monotone equiv to
    int bi = INT_MAX;                    //   reference log_sample argmax)

#pragma unroll
    for (int j = 0; j < NCHUNK; ++j) {
      const int e0 = abase + j * 1024 + t4;
      if (e0 < end) {   // e0%4==0 & E%4==0 -> e0+3 <= E-1 (safe f4 load)
        const float4 s4 = *(const float4*)(scores + e0);
        const float4 r4 = *(const float4*)(resid + e0);
        unsigned int m;
        if (byteFmt) {
          const unsigned int u = *(const unsigned int*)(vb + e0);
          m = ((u & 0x000000FFu) ? 1u : 0u) | ((u & 0x0000FF00u) ? 2u : 0u) |
              ((u & 0x00FF0000u) ? 4u : 0u) | ((u & 0xFF000000u) ? 8u : 0u);
        } else {
          const int4 u = *(const int4*)(vi + e0);
          m = (u.x ? 1u : 0u) | (u.y ? 2u : 0u) | (u.z ? 4u : 0u) | (u.w ? 8u : 0u);
        }
        const float ss[4] = {s4.x, s4.y, s4.z, s4.w};
        const float rr[4] = {r4.x, r4.y, r4.z, r4.w};
#pragma unroll
        for (int k = 0; k < 4; ++k) {
          const int e = e0 + k;
          const bool ok = ((m >> k) & 1u) && (e >= start) && (e < end);
          float t = LARGE_NEG;
          if (ok) {
            const float w = fmaxf(ss[k], SCORE_EPS);
            smax = fmaxf(smax, w);
            ssum += w;
            ++vcnt;
            t = __logf(w) + rr[k];
            // branchless online update (no divergent dual-exp paths)
            const float nm = fmaxf(om, t);
            os = os * __expf(om - nm) + __expf(t - nm);  // first iter: 0*0+1
            om = nm;
            if (t > bv || (t == bv && e < bi)) { bv = t; bi = e; }
          }
          c[j][k] = t;
        }
      } else {
#pragma unroll
        for (int k = 0; k < 4; ++k) c[j][k] = LARGE_NEG;
      }
    }

    // ---- single fused reduce: wave shuffle cascade over everything --------
#pragma unroll
    for (int o = 32; o >= 1; o >>= 1) {
      smax = fmaxf(smax, __shfl_xor(smax, o));
      ssum += __shfl_xor(ssum, o);
      vcnt += __shfl_xor(vcnt, o);
      const float m2v = __shfl_xor(om, o);
      const float s2v = __shfl_xor(os, o);
      const float nm = fmaxf(om, m2v);
      os = os * __expf(om - nm) + s2v * __expf(m2v - nm);
      om = nm;
      const float v2 = __shfl_xor(bv, o);
      const int i2 = __shfl_xor(bi, o);
      if (v2 > bv || (v2 == bv && i2 < bi)) { bv = v2; bi = i2; }
    }
    if (lane == 0) {
      redf[wid] = smax; redf[4 + wid] = ssum; redf[8 + wid] = (float)vcnt;
      redf[12 + wid] = om; redf[16 + wid] = os; redf[20 + wid] = bv;
      redi[wid] = bi;
    }
    __syncthreads();
    smax = fmaxf(fmaxf(redf[0], redf[1]), fmaxf(redf[2], redf[3]));
    ssum = (redf[4] + redf[5]) + (redf[6] + redf[7]);
    const float vc = (redf[8] + redf[9]) + (redf[10] + redf[11]);
    om = redf[12]; os = redf[16];
#pragma unroll
    for (int w = 1; w < 4; ++w) {        // online-merge 4 wave pairs
      const float mb = redf[12 + w], sb2 = redf[16 + w];
      const float nm = fmaxf(om, mb);
      os = os * __expf(om - nm) + sb2 * __expf(mb - nm);
      om = nm;
    }
    bv = redf[20]; bi = redi[0];
#pragma unroll
    for (int w = 1; w < 4; ++w) {
      const float v2 = redf[20 + w]; const int i2 = redi[w];
      if (v2 > bv || (v2 == bv && i2 < bi)) { bv = v2; bi = i2; }
    }

    // ---- per-graph scalars (computed by every thread; all scalar math) ----
    // ld1 = log M + log(ssum/M + 1/M + EPS) == log(ssum + 1 + M*EPS)  [r11]
    // max((log w - ld1) + r) == tmax - ld1; Sum exp(c-mj2) == os*exp(m2-mj2).
    const float M = fmaxf(smax, 1.f);
    const float ld1 = __logf(ssum + 1.f + M * F32EPS);
    const float m2 = om - ld1;               // max combined edge logit
    const float ss2 = stop_resid[g] - ld1;   // combined stop logit
    const float mj2 = fmaxf(m2, ss2);
    const float s2 = os * __expf(m2 - mj2);  // edge exp-sum at mj2 scale
    const float ld2 = mj2 + __logf(s2 + __expf(ss2 - mj2) + F32EPS);
    const float clean_stop = ss2 - ld2;
    const float invt = 1.f / fmaxf(vc + 1.f, 1.f);
    const float off3 = ld1 + ld2;            // clean = t - off3

    // ---- store pass: clean_log_edge from registers ------------------------
#pragma unroll
    for (int j = 0; j < NCHUNK; ++j) {
      const int e0 = abase + j * 1024 + t4;
      if (e0 < end) {
        float ov[4];
#pragma unroll
        for (int k = 0; k < 4; ++k) {
          const float t = c[j][k];
          ov[k] = (t != LARGE_NEG) ? (t - off3) : LARGE_NEG;
        }
        if (e0 >= start && e0 + 4 <= end) {
          *(float4*)(out + e0) = make_float4(ov[0], ov[1], ov[2], ov[3]);
        } else {
#pragma unroll
          for (int k = 0; k < 4; ++k) {
            const int e = e0 + k;
            if (e >= start && e < end) out[e] = ov[k];
          }
        }
      }
    }
    if (threadIdx.x == 0) {
      const bool anyvalid = (bi != INT_MAX);
      const float wclean = bv - off3;      // winner's clean_log_edge
      float bvls = LARGE_NEG;              // best log_sample_edge (ref formula)
      if (anyvalid) {
        const float p = (1.f - RANDP) * __expf(wclean) + RANDP * invt;
        bvls = __logf(fmaxf(p, PROB_EPS));
      }
      const float ssp = (1.f - RANDP) * __expf(clean_stop) + RANDP * invt;
      const float lss = __logf(fmaxf(ssp, PROB_EPS));
      const bool take_stop = (lss >= bvls);
      out[E + g]         = clean_stop;                         // output 1
      out[E + G + g]     = take_stop ? (float)end : (float)bi; // output 2
      out[E + 2 * G + g] = take_stop ? clean_stop : wclean;    // output 3
    }
    return;
  }

  // =================== fallback: 5-pass global reread (n > REGCAP) =========
  const int n = end - start;
  auto load_l = [&](int e) -> float {
    float s = scores[e];
    int v = byteFmt ? (int)vb[e] : vi[e];
    return v ? __logf(fmaxf(s, SCORE_EPS)) : LARGE_NEG;
  };

  float m1 = LARGE_NEG, vc = 0.f;
  for (int i = threadIdx.x; i < n; i += BLOCK) {
    float l = load_l(start + i);
    m1 = fmaxf(m1, l);
    if (l != LARGE_NEG) vc += 1.f;
  }
#pragma unroll
  for (int o = 32; o >= 1; o >>= 1) {
    m1 = fmaxf(m1, __shfl_xor(m1, o));
    vc += __shfl_xor(vc, o);
  }
  if (lane == 0) { redf[wid] = m1; redf[4 + wid] = vc; }
  __syncthreads();
  m1 = fmaxf(fmaxf(redf[0], redf[1]), fmaxf(redf[2], redf[3]));
  vc = (redf[4] + redf[5]) + (redf[6] + redf[7]);
  __syncthreads();

  const float mj1 = fmaxf(m1, 0.f);
  float s1 = 0.f;
  for (int i = threadIdx.x; i < n; i += BLOCK)
    s1 += __expf(load_l(start + i) - mj1);
#pragma unroll
  for (int o = 32; o >= 1; o >>= 1) s1 += __shfl_xor(s1, o);
  if (lane == 0) redf[wid] = s1;
  __syncthreads();
  s1 = (redf[0] + redf[1]) + (redf[2] + redf[3]);
  __syncthreads();
  const float ld1 = mj1 + __logf(s1 + __expf(-mj1) + F32EPS);

  float m2 = LARGE_NEG;
  for (int i = threadIdx.x; i < n; i += BLOCK) {
    float l = load_l(start + i);
    float cc = (l != LARGE_NEG) ? (l - ld1 + resid[start + i]) : LARGE_NEG;
    m2 = fmaxf(m2, cc);
  }
#pragma unroll
  for (int o = 32; o >= 1; o >>= 1) m2 = fmaxf(m2, __shfl_xor(m2, o));
  if (lane == 0) redf[wid] = m2;
  __syncthreads();
  m2 = fmaxf(fmaxf(redf[0], redf[1]), fmaxf(redf[2], redf[3]));
  __syncthreads();

  const float ss2 = stop_resid[g] - ld1;
  const float mj2 = fmaxf(m2, ss2);
  float s2 = 0.f;
  for (int i = threadIdx.x; i < n; i += BLOCK) {
    float l = load_l(start + i);
    float cc = (l != LARGE_NEG) ? (l - ld1 + resid[start + i]) : LARGE_NEG;
    s2 += __expf(cc - mj2);
  }
#pragma unroll
  for (int o = 32; o >= 1; o >>= 1) s2 += __shfl_xor(s2, o);
  if (lane == 0) redf[wid] = s2;
  __syncthreads();
  s2 = (redf[0] + redf[1]) + (redf[2] + redf[3]);
  __syncthreads();
  const float ld2 = mj2 + __logf(s2 + __expf(ss2 - mj2) + F32EPS);
  const float clean_stop = ss2 - ld2;
  const float invt = 1.f / fmaxf(vc + 1.f, 1.f);

  float bv = -INFINITY; int bi = INT_MAX; float bc = 0.f;
  for (int i = threadIdx.x; i < n; i += BLOCK) {
    const int e = start + i;
    float l = load_l(e);
    float cc = (l != LARGE_NEG) ? (l - ld1 + resid[e]) : LARGE_NEG;
    const bool v = (cc != LARGE_NEG);
    const float clean = cc - ld2;
    out[e] = v ? clean : LARGE_NEG;
    float ls;
    if (v) {
      const float p = (1.f - RANDP) * __expf(clean) + RANDP * invt;
      ls = __logf(fmaxf(p, PROB_EPS));
    } else ls = LARGE_NEG;
    if (ls > bv || (ls == bv && e < bi)) { bv = ls; bi = e; bc = clean; }
  }
#pragma unroll
  for (int o = 32; o >= 1; o >>= 1) {
    const float v2 = __shfl_xor(bv, o);
    const int i2 = __shfl_xor(bi, o);
    const float c2 = __shfl_xor(bc, o);
    if (v2 > bv || (v2 == bv && i2 < bi)) { bv = v2; bi = i2; bc = c2; }
  }
  if (lane == 0) { redf[wid] = bv; redf[4 + wid] = bc; redi[wid] = bi; }
  __syncthreads();
  if (threadIdx.x == 0) {
    bv = redf[0]; bi = redi[0]; bc = redf[4];
    for (int w = 1; w < 4; ++w) {
      if (redf[w] > bv || (redf[w] == bv && redi[w] < bi)) {
        bv = redf[w]; bi = redi[w]; bc = redf[4 + w];
      }
    }
    const float ssp = (1.f - RANDP) * __expf(clean_stop) + RANDP * invt;
    const float lss = __logf(fmaxf(ssp, PROB_EPS));
    const bool take_stop = (lss >= bv);
    out[E + g]         = clean_stop;
    out[E + G + g]     = take_stop ? (float)end : (float)bi;
    out[E + 2 * G + g] = take_stop ? clean_stop : bc;
  }
}

extern "C" void kernel_launch(void* const* d_in, const int* in_sizes, int n_in,
                              void* d_out, int out_size, void* d_ws, size_t ws_size,
                              hipStream_t stream) {
  const float* scores     = (const float*)d_in[0];
  const float* resid      = (const float*)d_in[1];
  const float* stop_resid = (const float*)d_in[2];
  const void*  validp     = d_in[3];
  const int*   batch      = (const int*)d_in[4];
  const int E = in_sizes[0];
  const int G = in_sizes[2];

  gfn_main<<<G, BLOCK, 0, stream>>>(scores, resid, stop_resid, validp, batch,
                                    (float*)d_out, E, G);
}